// Round 1
// baseline (165.719 us; speedup 1.0000x reference)
//
#include <hip/hip_runtime.h>
#include <hip/hip_bf16.h>

#define D_DIM 128
#define K_NBR 32
#define NU 4            // nodes per wave-group
#define NWAVES 16       // waves per block
#define TPB (NWAVES * 64)
#define NBLK 256

// d_ws layout: [0, 65536): GT2 bf16 [128 j-pairs][128 d][2 parity]
//              [65536, 66048): fused bias f32[128]

__device__ __forceinline__ float bfu_lo(unsigned int w) {
    union { unsigned int i; float f; } v; v.i = w << 16; return v.f;
}
__device__ __forceinline__ float bfu_hi(unsigned int w) {
    union { unsigned int i; float f; } v; v.i = w & 0xffff0000u; return v.f;
}

// G[d][j] = sum_k Wc[d][k] * (j<128 ? Wn[k][j] : Ws[k][j-128])
// bb[d]   = sum_k Wc[d][k] * (bn[k]+bs[k]) + bc[d]
__global__ void pinsage_precompute(const float* __restrict__ Wn_w, const float* __restrict__ Wn_b,
                                   const float* __restrict__ Ws_w, const float* __restrict__ Ws_b,
                                   const float* __restrict__ Wc_w, const float* __restrict__ Wc_b,
                                   unsigned short* __restrict__ GT2, float* __restrict__ bb) {
    const int d = threadIdx.x;   // 0..127
    const int b = blockIdx.x;
    if (b < 2 * D_DIM) {
        const int j = b;
        const float* Wsrc = (j < D_DIM) ? Wn_w : Ws_w;
        const int jj = j & (D_DIM - 1);
        float acc = 0.f;
        #pragma unroll 8
        for (int k = 0; k < D_DIM; ++k)
            acc += Wc_w[d * D_DIM + k] * Wsrc[k * D_DIM + jj];
        __hip_bfloat16 hb = __float2bfloat16(acc);
        unsigned short us = *reinterpret_cast<unsigned short*>(&hb);
        // interleave j-pairs: element (j,d) at [(j>>1)*128 + d]*2 + (j&1)
        GT2[(((j >> 1) * D_DIM) + d) * 2 + (j & 1)] = us;
    } else {
        float acc = Wc_b[d];
        #pragma unroll 8
        for (int k = 0; k < D_DIM; ++k)
            acc += Wc_w[d * D_DIM + k] * (Wn_b[k] + Ws_b[k]);
        bb[d] = acc;
    }
}

__global__ __launch_bounds__(TPB, 4) void pinsage_main(
    const int* __restrict__ node_ids,
    const float* __restrict__ emb,
    const int* __restrict__ nbr_ids,
    const float* __restrict__ nbr_w,
    const unsigned short* __restrict__ GT2,
    const float* __restrict__ bbg,
    float* __restrict__ out,
    int B) {

    __shared__ unsigned short sGT[2 * D_DIM * D_DIM];   // 64 KB fused weight, bf16
    __shared__ float sU[NWAVES][NU][2 * D_DIM];         // 64 KB per-wave [weighted|x_self]
    __shared__ int   sId[NWAVES][NU][K_NBR];            // 8 KB
    __shared__ float sW[NWAVES][NU][K_NBR];             // 8 KB   total 144 KB -> 1 block/CU

    const int tid = threadIdx.x;

    // one-time stage of G^T into LDS (64 KB, 16B per thread per iter)
    {
        const uint4* src = reinterpret_cast<const uint4*>(GT2);
        uint4* dst = reinterpret_cast<uint4*>(sGT);
        #pragma unroll
        for (int i = 0; i < 4; ++i)
            dst[tid + i * TPB] = src[tid + i * TPB];
    }
    __syncthreads();   // only block-wide barrier; waves independent afterwards

    const int wave = tid >> 6;
    const int lane = tid & 63;
    const int h = lane >> 5;   // half-wave
    const int c = lane & 31;

    const float2 bbv = *reinterpret_cast<const float2*>(&bbg[2 * lane]);  // dims 2l,2l+1

    const int nGroups = (B + NU - 1) / NU;
    const int gstride = gridDim.x * NWAVES;

    for (int g = blockIdx.x * NWAVES + wave; g < nGroups; g += gstride) {
        const int base = g * NU;

        // ---- Phase A: neighbor ids/weights + self embedding (coalesced) ----
        #pragma unroll
        for (int p = 0; p < 2; ++p) {
            const int i = 2 * p + h;                 // half-wave h handles nodes h, 2+h
            const int n = base + i;
            const int nid = (n < B) ? node_ids[n] : 0;
            const size_t rb = (size_t)nid * K_NBR;
            sId[wave][i][c] = nbr_ids[rb + c];
            sW[wave][i][c]  = nbr_w[rb + c];
            const float4 xs = reinterpret_cast<const float4*>(emb + (size_t)nid * D_DIM)[c];
            *reinterpret_cast<float4*>(&sU[wave][i][D_DIM + 4 * c]) = xs;
        }

        // ---- Phase B: weighted neighbor reduction (random 512B row gathers) ----
        #pragma unroll
        for (int p = 0; p < 2; ++p) {
            const int i = 2 * p + h;
            float4 a0 = make_float4(0.f, 0.f, 0.f, 0.f);
            float4 a1 = make_float4(0.f, 0.f, 0.f, 0.f);
            #pragma unroll 4
            for (int k = 0; k < K_NBR; k += 2) {
                const int id0 = sId[wave][i][k];       // uniform per half-wave (DS in-order, same wave)
                const int id1 = sId[wave][i][k + 1];
                const float w0 = sW[wave][i][k];
                const float w1 = sW[wave][i][k + 1];
                const float4 r0 = reinterpret_cast<const float4*>(emb + (size_t)id0 * D_DIM)[c];
                const float4 r1 = reinterpret_cast<const float4*>(emb + (size_t)id1 * D_DIM)[c];
                a0.x = fmaf(w0, r0.x, a0.x); a0.y = fmaf(w0, r0.y, a0.y);
                a0.z = fmaf(w0, r0.z, a0.z); a0.w = fmaf(w0, r0.w, a0.w);
                a1.x = fmaf(w1, r1.x, a1.x); a1.y = fmaf(w1, r1.y, a1.y);
                a1.z = fmaf(w1, r1.z, a1.z); a1.w = fmaf(w1, r1.w, a1.w);
            }
            a0.x += a1.x; a0.y += a1.y; a0.z += a1.z; a0.w += a1.w;
            *reinterpret_cast<float4*>(&sU[wave][i][4 * c]) = a0;
        }

        // ---- Phase C: fused GEMM  z[d] = relu(sum_j G[d][j]*u[j] + bb[d]) ----
        // lane owns dims d0=2l, d1=2l+1 for all NU nodes; G read once per 4 nodes
        float acc[NU][2];
        #pragma unroll
        for (int n = 0; n < NU; ++n) { acc[n][0] = 0.f; acc[n][1] = 0.f; }

        const unsigned short* gtp = &sGT[4 * lane];
        #pragma unroll 4
        for (int j2 = 0; j2 < D_DIM; ++j2) {
            // 4 bf16: (d0,j0)(d0,j1)(d1,j0)(d1,j1), contiguous 8B per lane -> conflict-free
            const uint2 gw = *reinterpret_cast<const uint2*>(gtp + j2 * 256);
            const float g00 = bfu_lo(gw.x), g01 = bfu_hi(gw.x);
            const float g10 = bfu_lo(gw.y), g11 = bfu_hi(gw.y);
            #pragma unroll
            for (int n = 0; n < NU; ++n) {
                const float2 uu = *reinterpret_cast<const float2*>(&sU[wave][n][2 * j2]); // broadcast
                acc[n][0] = fmaf(g00, uu.x, fmaf(g01, uu.y, acc[n][0]));
                acc[n][1] = fmaf(g10, uu.x, fmaf(g11, uu.y, acc[n][1]));
            }
        }

        // ---- epilogue: bias + relu + coalesced store ----
        #pragma unroll
        for (int n = 0; n < NU; ++n) {
            const int node = base + n;
            if (node < B) {
                float2 r;
                r.x = fmaxf(acc[n][0] + bbv.x, 0.f);
                r.y = fmaxf(acc[n][1] + bbv.y, 0.f);
                *reinterpret_cast<float2*>(&out[(size_t)node * D_DIM + 2 * lane]) = r;
            }
        }
    }
}

extern "C" void kernel_launch(void* const* d_in, const int* in_sizes, int n_in,
                              void* d_out, int out_size, void* d_ws, size_t ws_size,
                              hipStream_t stream) {
    const int*   node_ids = (const int*)  d_in[0];
    const float* emb      = (const float*)d_in[1];
    const int*   nbr_ids  = (const int*)  d_in[2];
    const float* nbr_w    = (const float*)d_in[3];
    const float* Wn_w     = (const float*)d_in[4];
    const float* Wn_b     = (const float*)d_in[5];
    const float* Ws_w     = (const float*)d_in[6];
    const float* Ws_b     = (const float*)d_in[7];
    const float* Wc_w     = (const float*)d_in[8];
    const float* Wc_b     = (const float*)d_in[9];
    const int B = in_sizes[0];

    unsigned short* GT2 = (unsigned short*)d_ws;
    float* bb = (float*)((char*)d_ws + 65536);
    float* out = (float*)d_out;

    pinsage_precompute<<<2 * D_DIM + 1, D_DIM, 0, stream>>>(Wn_w, Wn_b, Ws_w, Ws_b, Wc_w, Wc_b, GT2, bb);
    pinsage_main<<<NBLK, TPB, 0, stream>>>(node_ids, emb, nbr_ids, nbr_w, GT2, bb, out, B);
}